// Round 1
// baseline (907.452 us; speedup 1.0000x reference)
//
#include <hip/hip_runtime.h>

typedef _Float16 f16x8 __attribute__((ext_vector_type(8)));
typedef _Float16 f16x2 __attribute__((ext_vector_type(2)));
typedef __fp16 fp16x2_raw __attribute__((ext_vector_type(2)));
typedef float f32x4 __attribute__((ext_vector_type(4)));
typedef float f32x2 __attribute__((ext_vector_type(2)));
typedef unsigned int uint32;
typedef unsigned short ushort16;
typedef unsigned char uchar;

#define EPS_BN 1e-5f

__device__ __forceinline__ uint32 pk16(float a, float b){
  fp16x2_raw h = __builtin_amdgcn_cvt_pkrtz(a, b);
  return *(uint32*)&h;
}
__device__ __forceinline__ ushort16 f2h(float f){
  _Float16 h = (_Float16)f;
  union { _Float16 h; ushort16 u; } c; c.h = h; return c.u;
}
__device__ __forceinline__ uchar f2fp8(float f){
  uint32 p = __builtin_amdgcn_cvt_pk_fp8_f32(f, f, 0, false);
  return (uchar)(p & 0xff);
}
__device__ __forceinline__ f32x2 fp8pair_lo(uint32 w){
  return __builtin_amdgcn_cvt_pk_f32_fp8(w, false);
}
__device__ __forceinline__ f32x2 fp8pair_hi(uint32 w){
  return __builtin_amdgcn_cvt_pk_f32_fp8(w, true);
}

// ---------------- weight conversion: f32 row-major -> f16 MFMA-fragment-linear ----------------
struct WEnt { const float* s; const float* s2; ushort16* d; int KD, MD, nfrag; };
struct WConv { WEnt e[16]; };

__global__ __launch_bounds__(256) void conv_w_k(WConv a){
  WEnt t = a.e[blockIdx.y];
  int fid = blockIdx.x * 256 + threadIdx.x;
  if (fid >= t.nfrag) return;
  int lane = fid & 63, sm = fid >> 6;
  int MT = t.MD >> 4;
  int s = sm / MT, m = sm - s * MT;
  int row = m * 16 + (lane & 15);
  int col = s * 32 + (lane >> 4) * 8;
  const float* sp = t.s;
  if (t.s2 && row >= 128){ sp = t.s2; row -= 128; }
  const float* p = sp + (size_t)row * t.KD + col;
  uint4 o;
  o.x = pk16(p[0], p[1]); o.y = pk16(p[2], p[3]);
  o.z = pk16(p[4], p[5]); o.w = pk16(p[6], p[7]);
  *(uint4*)(t.d + (size_t)fid * 8) = o;
}

__global__ __launch_bounds__(256) void conv2_k(const float* __restrict__ a, const float* __restrict__ b,
                                               ushort16* __restrict__ da, ushort16* __restrict__ db, int n){
  const float* s = blockIdx.y ? b : a;
  ushort16* d = blockIdx.y ? db : da;
  int i = (blockIdx.x * 256 + threadIdx.x) * 4;
  if (i >= n) return;
  float4 v = *(const float4*)(s + i);
  uint2 p;
  p.x = pk16(v.x, v.y);
  p.y = pk16(v.z, v.w);
  *(uint2*)(d + i) = p;
}

// ---------------- CSR build ----------------
__global__ void hist_k(const int* __restrict__ dst, int* __restrict__ cnt, int E){
  int i = blockIdx.x * blockDim.x + threadIdx.x;
  int stride = gridDim.x * blockDim.x;
  for (; i < E; i += stride) atomicAdd(&cnt[dst[i]], 1);
}

__global__ __launch_bounds__(256) void scan_part_k(const int* __restrict__ cnt, int* __restrict__ bsum, int N){
  int tid = threadIdx.x, lane = tid & 63, wv = tid >> 6;
  int base = blockIdx.x * 1024 + tid * 4;
  int ts = 0;
  #pragma unroll
  for (int j = 0; j < 4; j++) if (base + j < N) ts += cnt[base + j];
  #pragma unroll
  for (int d = 1; d < 64; d <<= 1) ts += __shfl_xor(ts, d);
  __shared__ int wt[4];
  if (lane == 0) wt[wv] = ts;
  __syncthreads();
  if (tid == 0) bsum[blockIdx.x] = wt[0] + wt[1] + wt[2] + wt[3];
}

__global__ __launch_bounds__(64) void scan_top_k(int* __restrict__ bsum, int nb){
  int tid = threadIdx.x;
  int v = (tid < nb) ? bsum[tid] : 0;
  int inc = v;
  #pragma unroll
  for (int d = 1; d < 64; d <<= 1){
    int t = __shfl_up(inc, d);
    if (tid >= d) inc += t;
  }
  if (tid < nb) bsum[tid] = inc - v;
}

// stage 3: write row_off/cursor (+ per-bucket cursors for the binned fill)
__global__ __launch_bounds__(256) void scan_out_k(const int* __restrict__ cnt, const int* __restrict__ bsum,
                                                  int* __restrict__ row_off, int* __restrict__ cursor,
                                                  int* __restrict__ bcur,
                                                  int N, int E, int shift){
  int tid = threadIdx.x, lane = tid & 63, wv = tid >> 6;
  int base = blockIdx.x * 1024 + tid * 4;
  int c[4]; int ts = 0;
  #pragma unroll
  for (int j = 0; j < 4; j++){ c[j] = (base + j < N) ? cnt[base + j] : 0; ts += c[j]; }
  int inc = ts;
  #pragma unroll
  for (int d = 1; d < 64; d <<= 1){
    int t = __shfl_up(inc, d);
    if (lane >= d) inc += t;
  }
  int wexcl = inc - ts;
  __shared__ int wt[4];
  if (lane == 63) wt[wv] = inc;
  __syncthreads();
  int woff = 0;
  for (int w = 0; w < 4; w++) if (w < wv) woff += wt[w];
  int off = bsum[blockIdx.x] + woff + wexcl;
  int mask = (1 << shift) - 1;
  #pragma unroll
  for (int j = 0; j < 4; j++){
    int d = base + j;
    if (d < N){
      row_off[d] = off; cursor[d] = off;
      if ((d & mask) == 0) bcur[d >> shift] = off;
      off += c[j];
    }
  }
  if (blockIdx.x == 0 && tid == 0) row_off[N] = E;
}

// ---------------- bucketed fill: pass 1, LDS-binned grouping by dst bucket ----------------
#define BIN_TB 512
#define BIN_TILE 4096
__global__ __launch_bounds__(512) void bin_k(const int* __restrict__ src, const int* __restrict__ dst,
                                             int* __restrict__ bcur, uint2* __restrict__ ebuf,
                                             int E, int shift, int B){
  __shared__ int lhist[128];
  __shared__ int lstart[128];
  __shared__ int gbase[128];
  __shared__ uint2 lpair[BIN_TILE];
  int tid = threadIdx.x;
  int base = blockIdx.x * BIN_TILE;
  int cnt = E - base; if (cnt > BIN_TILE) cnt = BIN_TILE;
  if (tid < 128) lhist[tid] = 0;
  __syncthreads();
  int myb[8], myrank[8];
  uint2 myp[8];
  int nmine = 0;
  #pragma unroll
  for (int j = 0; j < 8; j++){
    int i = tid + j * BIN_TB;
    if (i < cnt){
      int s = src[base + i], d = dst[base + i];
      int b = d >> shift;
      myp[nmine] = make_uint2((uint32)s, (uint32)d);
      myb[nmine] = b;
      myrank[nmine] = atomicAdd(&lhist[b], 1);
      nmine++;
    }
  }
  __syncthreads();
  if (tid == 0){
    int run = 0;
    for (int b = 0; b < B; b++){ lstart[b] = run; run += lhist[b]; }
  }
  __syncthreads();
  if (tid < B) gbase[tid] = atomicAdd(&bcur[tid], lhist[tid]);
  for (int j = 0; j < nmine; j++){
    lpair[lstart[myb[j]] + myrank[j]] = myp[j];
  }
  __syncthreads();
  for (int i = tid; i < cnt; i += BIN_TB){
    uint2 p = lpair[i];
    int b = (int)(p.y >> shift);
    ebuf[gbase[b] + (i - lstart[b])] = p;
  }
}

// ---------------- bucketed fill: pass 2, bucket-local cursor scatter ----------------
__global__ __launch_bounds__(512) void bfill_k(const uint2* __restrict__ ebuf, const int* __restrict__ row_off,
                                               int* __restrict__ cursor, int* __restrict__ esrc,
                                               int shift, int N){
  int b = blockIdx.x;
  int d0 = b << shift;
  int d1 = (b + 1) << shift; if (d1 > N) d1 = N;
  if (d0 >= N) return;
  int e0 = row_off[d0], e1 = row_off[d1];
  for (int i = e0 + (int)threadIdx.x; i < e1; i += 512){
    uint2 p = ebuf[i];
    int pos = atomicAdd(&cursor[p.y], 1);
    esrc[pos] = (int)p.x;
  }
}

// ---------------- fused QKV projection, LDS-staged coalesced stores ----------------
__global__ __launch_bounds__(256) void gemm_qkv_k(
    const ushort16* __restrict__ Xq, const ushort16* __restrict__ Xkv,
    const ushort16* __restrict__ Wq, const ushort16* __restrict__ Wk, const ushort16* __restrict__ Wv,
    ushort16* __restrict__ Qo, uchar* __restrict__ K8, uchar* __restrict__ V8, int N)
{
  __shared__ _Float16 Qs[4][16 * 136];
  __shared__ uchar Ks[4][16 * 136];
  __shared__ uchar Vs[4][16 * 136];
  int lane = threadIdx.x & 63, wv = threadIdx.x >> 6;
  int l15 = lane & 15, kq = lane >> 4;
  int rowbase = (blockIdx.x * 4 + wv) * 16;
  int row = rowbase + l15;
  int rc = row < N ? row : N - 1;
  const f16x8* aq = (const f16x8*)(Xq + (size_t)rc * 128 + kq * 8);
  const f16x8* ak = (const f16x8*)(Xkv + (size_t)rc * 128 + kq * 8);
  f16x8 Aq[4], Ak[4];
  #pragma unroll
  for (int s = 0; s < 4; s++){ Aq[s] = aq[s * 4]; Ak[s] = ak[s * 4]; }
  const f16x8* Wqf = (const f16x8*)Wq;
  const f16x8* Wkf = (const f16x8*)Wk;
  const f16x8* Wvf = (const f16x8*)Wv;
  f32x4 q[8], k[8], v[8];
  #pragma unroll
  for (int m = 0; m < 8; m++){ q[m] = (f32x4)(0.f); k[m] = (f32x4)(0.f); v[m] = (f32x4)(0.f); }
  #pragma unroll
  for (int s = 0; s < 4; s++){
    #pragma unroll
    for (int m = 0; m < 8; m++){
      int fi = (s * 8 + m) * 64 + lane;
      q[m] = __builtin_amdgcn_mfma_f32_16x16x32_f16(Aq[s], Wqf[fi], q[m], 0, 0, 0);
      k[m] = __builtin_amdgcn_mfma_f32_16x16x32_f16(Ak[s], Wkf[fi], k[m], 0, 0, 0);
      v[m] = __builtin_amdgcn_mfma_f32_16x16x32_f16(Ak[s], Wvf[fi], v[m], 0, 0, 0);
    }
  }
  #pragma unroll
  for (int m = 0; m < 8; m++){
    int col = m * 16 + l15;
    #pragma unroll
    for (int r = 0; r < 4; r++){
      int lrow = kq * 4 + r;
      Qs[wv][lrow * 136 + col] = (_Float16)q[m][r];
      Ks[wv][lrow * 136 + col] = f2fp8(k[m][r]);
      Vs[wv][lrow * 136 + col] = f2fp8(v[m][r]);
    }
  }
  #pragma unroll
  for (int p = 0; p < 4; p++){
    int lrow = p * 4 + (lane >> 4);
    int rr = rowbase + lrow;
    int col8 = l15 * 8;
    if (rr < N){
      uint4 qv = *(uint4*)&Qs[wv][lrow * 136 + col8];
      *(uint4*)(Qo + (size_t)rr * 128 + col8) = qv;
      uint2 kv = *(uint2*)&Ks[wv][lrow * 136 + col8];
      *(uint2*)(K8 + (size_t)rr * 128 + col8) = kv;
      uint2 vv = *(uint2*)&Vs[wv][lrow * 136 + col8];
      *(uint2*)(V8 + (size_t)rr * 128 + col8) = vv;
    }
  }
}

// ---------------- generic GEMM, swizzled W, f16 in/out, LDS-staged stores ----------------
// EPI: 1=relu, 2=sigmoid, 3=+res(f16), 4=gate w/ res(f16), 5=+BN(res), 6=gate w/ BN(res)
// ABN=1: apply BN to A on load. ST=1: accumulate column stats.
template<int KD, int MD, int EPI, int ABN, int ST, int GS>
__global__ __launch_bounds__(256) void gemm_k(
    const ushort16* __restrict__ X, const ushort16* __restrict__ W,
    const float* __restrict__ bias, const float* __restrict__ bias2,
    const ushort16* __restrict__ resb, const ushort16* __restrict__ gatep,
    const float* __restrict__ rstats, const float* __restrict__ rg, const float* __restrict__ rb,
    const float* __restrict__ astats, const float* __restrict__ ag, const float* __restrict__ ab,
    ushort16* __restrict__ outb, float* __restrict__ stats_out, int N, float invN)
{
  constexpr int KS = KD / 32;
  constexpr int MT = MD / 16;
  constexpr int LSTR = MD + 8;
  __shared__ _Float16 Os[4][16 * LSTR];
  int lane = threadIdx.x & 63, wv = threadIdx.x >> 6;
  int l15 = lane & 15, kq = lane >> 4;
  int rowbase = (blockIdx.x * 4 + wv) * 16;
  int row = rowbase + l15;
  int rc = row < N ? row : N - 1;
  const f16x8* ap = (const f16x8*)(X + (size_t)rc * KD + kq * 8);
  f16x8 a[KS];
  #pragma unroll
  for (int s = 0; s < KS; s++) a[s] = ap[s * 4];
  if constexpr (ABN){
    #pragma unroll
    for (int s = 0; s < KS; s++){
      #pragma unroll
      for (int j = 0; j < 8; j++){
        int c = s * 32 + kq * 8 + j;
        float mm = astats[c] * invN;
        float var = astats[128 + c] * invN - mm * mm;
        float rs = rsqrtf(var + EPS_BN);
        float scc = rs * ag[c];
        float shh = ab[c] - mm * scc;
        a[s][j] = (_Float16)((float)a[s][j] * scc + shh);
      }
    }
  }
  const f16x8* Wf = (const f16x8*)W;
  f32x4 acc[MT];
  #pragma unroll
  for (int m = 0; m < MT; m++) acc[m] = (f32x4)(0.f);
  #pragma unroll
  for (int s = 0; s < KS; s++){
    #pragma unroll
    for (int m = 0; m < MT; m++){
      acc[m] = __builtin_amdgcn_mfma_f32_16x16x32_f16(a[s], Wf[(s * MT + m) * 64 + lane], acc[m], 0, 0, 0);
    }
  }
  float ps[MT], ps2[MT];
  if constexpr (ST){
    #pragma unroll
    for (int m = 0; m < MT; m++){ ps[m] = 0.f; ps2[m] = 0.f; }
  }
  int r0 = rowbase + kq * 4;
  #pragma unroll
  for (int m = 0; m < MT; m++){
    int col = m * 16 + l15;
    float bv;
    if (bias2 && col >= 128) bv = bias2[col - 128];
    else bv = bias[col];
    float sc = 0.f, sh = 0.f;
    if constexpr (EPI == 5 || EPI == 6){
      float mm = rstats[col] * invN;
      float var = rstats[128 + col] * invN - mm * mm;
      float rs = rsqrtf(var + EPS_BN);
      sc = rs * rg[col]; sh = rb[col] - mm * sc;
    }
    #pragma unroll
    for (int r = 0; r < 4; r++){
      int rr = r0 + r;
      float v;
      {
        int rrc = rr < N ? rr : N - 1;
        v = acc[m][r] + bv;
        if constexpr (EPI == 1) v = fmaxf(v, 0.f);
        if constexpr (EPI == 2) v = 1.f / (1.f + __expf(-v));
        if constexpr (EPI == 3){
          union { ushort16 u; _Float16 h; } cv; cv.u = resb[(size_t)rrc * 128 + col];
          v += (float)cv.h;
        }
        if constexpr (EPI == 5){
          union { ushort16 u; _Float16 h; } cv; cv.u = resb[(size_t)rrc * 128 + col];
          v += (float)cv.h * sc + sh;
        }
        if constexpr (EPI == 4 || EPI == 6){
          union { ushort16 u; _Float16 h; } gv; gv.u = gatep[(size_t)rrc * GS + col];
          union { ushort16 u; _Float16 h; } cv; cv.u = resb[(size_t)rrc * 128 + col];
          float g = (float)gv.h;
          float rv = (float)cv.h;
          if constexpr (EPI == 6) rv = rv * sc + sh;
          v = (1.f - g) * rv + g * v;
        }
      }
      Os[wv][(kq * 4 + r) * LSTR + col] = (_Float16)v;
      if constexpr (ST){
        if (rr < N){ ps[m] += v; ps2[m] += v * v; }
      }
    }
  }
  if constexpr (MD == 128){
    #pragma unroll
    for (int p = 0; p < 4; p++){
      int lrow = p * 4 + (lane >> 4);
      int rr = rowbase + lrow;
      int col8 = l15 * 8;
      if (rr < N){
        uint4 ov = *(uint4*)&Os[wv][lrow * LSTR + col8];
        *(uint4*)(outb + (size_t)rr * MD + col8) = ov;
      }
    }
  } else {
    #pragma unroll
    for (int p = 0; p < 8; p++){
      int lrow = p * 2 + (lane >> 5);
      int rr = rowbase + lrow;
      int col8 = (lane & 31) * 8;
      if (rr < N){
        uint4 ov = *(uint4*)&Os[wv][lrow * LSTR + col8];
        *(uint4*)(outb + (size_t)rr * MD + col8) = ov;
      }
    }
  }
  if constexpr (ST){
    __shared__ float sst[4][128];
    __shared__ float sst2[4][128];
    #pragma unroll
    for (int m = 0; m < MT; m++){
      float s = ps[m], s2 = ps2[m];
      s  += __shfl_xor(s, 16);  s  += __shfl_xor(s, 32);
      s2 += __shfl_xor(s2, 16); s2 += __shfl_xor(s2, 32);
      if (lane < 16){ sst[wv][m * 16 + l15] = s; sst2[wv][m * 16 + l15] = s2; }
    }
    __syncthreads();
    int tid = threadIdx.x;
    if (tid < 128){
      atomicAdd(&stats_out[tid], sst[0][tid] + sst[1][tid] + sst[2][tid] + sst[3][tid]);
    } else {
      int c = tid - 128;
      atomicAdd(&stats_out[tid], sst2[0][c] + sst2[1][c] + sst2[2][c] + sst2[3][c]);
    }
  }
}

// ---------------- fused dual-attention (fp8 K, fp8 V) ----------------
// VALU-lean rework: packed f32x2 math (v_pk_fma_f32), med3 clamp + exp2 with
// log2(e) folded into Q scale, 32-bit shared voffset addressing (one
// (s<<7)+j*4 offset for all 4 K/V arrays; SGPR base + voffset form).
__global__ __launch_bounds__(256) void attn2_k(
    const ushort16* __restrict__ Qa, const ushort16* __restrict__ Qb,
    const uchar* __restrict__ K8a, const uchar* __restrict__ V8a,
    const uchar* __restrict__ K8b, const uchar* __restrict__ V8b,
    const int* __restrict__ row_off, const int* __restrict__ esrc,
    ushort16* __restrict__ cat, int N)
{
  int wv = threadIdx.x >> 6, lane = threadIdx.x & 63;
  int n = blockIdx.x * 4 + wv;
  if (n >= N) return;
  int h = lane >> 5, j = lane & 31;
  uint32 j4 = (uint32)j * 4u;
  // Q scale: 1/sqrt(DH) * log2(e), so score = exp2(clamped dot)
  const float QS = 0.25f * 1.44269504088896f;
  const float CL = 7.21347520444482f; // 5 * log2(e)
  uint2 qau = *(const uint2*)(Qa + (size_t)n * 128 + j4);
  uint2 qbu = *(const uint2*)(Qb + (size_t)n * 128 + j4);
  f16x2 qa01h = *(f16x2*)&qau.x, qa23h = *(f16x2*)&qau.y;
  f16x2 qb01h = *(f16x2*)&qbu.x, qb23h = *(f16x2*)&qbu.y;
  f32x2 qa01, qa23, qb01, qb23;
  qa01.x = (float)qa01h.x * QS; qa01.y = (float)qa01h.y * QS;
  qa23.x = (float)qa23h.x * QS; qa23.y = (float)qa23h.y * QS;
  qb01.x = (float)qb01h.x * QS; qb01.y = (float)qb01h.y * QS;
  qb23.x = (float)qb23h.x * QS; qb23.y = (float)qb23h.y * QS;
  int e0 = row_off[n], e1 = row_off[n + 1];
  int deg = e1 - e0;
  int itmax = (deg + 1) >> 1;
  f32x2 a01 = (f32x2)(0.f), a23 = (f32x2)(0.f);
  f32x2 b01 = (f32x2)(0.f), b23 = (f32x2)(0.f);
  f32x2 zab = (f32x2)(0.f);
  int e = e0 + h;
  int s = (e < e1) ? esrc[e] : -1;
  int sc0 = s < 0 ? 0 : s;
  uint32 off = ((uint32)sc0 << 7) + j4;
  uint32 kwa = *(const uint32*)(K8a + off);
  uint32 kwb = *(const uint32*)(K8b + off);
  uint32 vwa = *(const uint32*)(V8a + off);
  uint32 vwb = *(const uint32*)(V8b + off);
  for (int it = 0; it < itmax; ++it){
    int e2 = e + 2;
    int s2 = (e2 < e1) ? esrc[e2] : -1;
    int s2c = s2 < 0 ? 0 : s2;
    uint32 off2 = ((uint32)s2c << 7) + j4;
    uint32 kwa2 = *(const uint32*)(K8a + off2);
    uint32 kwb2 = *(const uint32*)(K8b + off2);
    uint32 vwa2 = *(const uint32*)(V8a + off2);
    uint32 vwb2 = *(const uint32*)(V8b + off2);
    if (s >= 0){
      f32x2 ka01 = fp8pair_lo(kwa), ka23 = fp8pair_hi(kwa);
      f32x2 kb01 = fp8pair_lo(kwb), kb23 = fp8pair_hi(kwb);
      f32x2 dda = ka01 * qa01 + ka23 * qa23;   // v_pk_mul + v_pk_fma
      f32x2 ddb = kb01 * qb01 + kb23 * qb23;
      float da = dda.x + dda.y;
      float db = ddb.x + ddb.y;
      da += __shfl_xor(da, 1); da += __shfl_xor(da, 2);
      db += __shfl_xor(db, 1); db += __shfl_xor(db, 2);
      float sa = __builtin_amdgcn_exp2f(__builtin_amdgcn_fmed3f(da, -CL, CL));
      float sb = __builtin_amdgcn_exp2f(__builtin_amdgcn_fmed3f(db, -CL, CL));
      f32x2 va01 = fp8pair_lo(vwa), va23 = fp8pair_hi(vwa);
      f32x2 vb01 = fp8pair_lo(vwb), vb23 = fp8pair_hi(vwb);
      f32x2 sa2; sa2.x = sa; sa2.y = sa;
      f32x2 sb2; sb2.x = sb; sb2.y = sb;
      a01 += sa2 * va01; a23 += sa2 * va23;    // v_pk_fma_f32
      b01 += sb2 * vb01; b23 += sb2 * vb23;
      f32x2 sab; sab.x = sa; sab.y = sb;
      zab += sab;                               // one packed add for za,zb
    }
    e = e2; s = s2;
    kwa = kwa2; kwb = kwb2; vwa = vwa2; vwb = vwb2;
  }
  // cross-half reduce (edge e vs e+1 halves)
  {
    f32x2 t;
    t.x = __shfl_xor(a01.x, 32); t.y = __shfl_xor(a01.y, 32); a01 += t;
    t.x = __shfl_xor(a23.x, 32); t.y = __shfl_xor(a23.y, 32); a23 += t;
    t.x = __shfl_xor(b01.x, 32); t.y = __shfl_xor(b01.y, 32); b01 += t;
    t.x = __shfl_xor(b23.x, 32); t.y = __shfl_xor(b23.y, 32); b23 += t;
    t.x = __shfl_xor(zab.x, 32); t.y = __shfl_xor(zab.y, 32); zab += t;
  }
  uint2 o;
  if (h == 0){
    float rz = __builtin_amdgcn_rcpf(zab.x);
    o.x = pk16(a01.x * rz, a01.y * rz);
    o.y = pk16(a23.x * rz, a23.y * rz);
    *(uint2*)(cat + (size_t)n * 256 + j4) = o;
  } else {
    float rz = __builtin_amdgcn_rcpf(zab.y);
    o.x = pk16(b01.x * rz, b01.y * rz);
    o.y = pk16(b23.x * rz, b23.y * rz);
    *(uint2*)(cat + (size_t)n * 256 + 128 + j4) = o;
  }
}

// ---------------- BatchNorm apply (f16 in, f32 out) ----------------
__global__ __launch_bounds__(256) void bn_apply_k(
    const ushort16* __restrict__ x, const float* __restrict__ stats,
    const float* __restrict__ gamma, const float* __restrict__ beta,
    float* __restrict__ outf, int total4, float invN)
{
  int i = blockIdx.x * 256 + threadIdx.x;
  if (i >= total4) return;
  uint2 xp = *(const uint2*)(x + (size_t)i * 4);
  f16x2 x01 = *(f16x2*)&xp.x, x23 = *(f16x2*)&xp.y;
  float xv[4] = {(float)x01.x, (float)x01.y, (float)x23.x, (float)x23.y};
  int c0 = (i * 4) & 127;
  float o[4];
  #pragma unroll
  for (int j = 0; j < 4; j++){
    int c = c0 + j;
    float m = stats[c] * invN;
    float var = stats[128 + c] * invN - m * m;
    float rstd = rsqrtf(var + EPS_BN);
    o[j] = (xv[j] - m) * rstd * gamma[c] + beta[c];
  }
  *(float4*)(outf + (size_t)i * 4) = make_float4(o[0], o[1], o[2], o[3]);
}

// ---------------- host ----------------
extern "C" void kernel_launch(void* const* d_in, const int* in_sizes, int n_in,
                              void* d_out, int out_size, void* d_ws, size_t ws_size,
                              hipStream_t stream) {
  const float* h   = (const float*)d_in[0];
  const float* sv  = (const float*)d_in[1];
  const int* src   = (const int*)d_in[2];
  const int* dst   = (const int*)d_in[3];
  const int N = in_sizes[0] / 128;
  const int E = in_sizes[2];

  char* wsb = (char*)d_ws;
  size_t o = 0;
  auto take = [&](size_t bytes)->size_t{
    size_t r = o;
    o = (o + bytes + 255) & ~(size_t)255;
    return r;
  };
  size_t cnt_off    = take((size_t)N * 4);
  size_t stats_off  = take(4 * 256 * 4);
  size_t rowoff_off = take((size_t)(N + 1) * 4);
  size_t cursor_off = take((size_t)N * 4);
  size_t bsum_off   = take(256 * 4);
  size_t bcur_off   = take(128 * 4);
  size_t esrc_off   = take((size_t)E * 4);
  size_t ebuf_off   = take((size_t)E * 8);
  size_t wpool_off  = take((size_t)376832 * 2);
  size_t hf_off     = take((size_t)N * 128 * 2);
  size_t svf_off    = take((size_t)N * 128 * 2);
  size_t cath_off   = take((size_t)N * 256 * 2);
  size_t catsv_off  = take((size_t)N * 256 * 2);
  size_t K81_off    = take((size_t)N * 128);
  size_t V81_off    = take((size_t)N * 128);
  size_t K82_off    = take((size_t)N * 128);
  size_t V82_off    = take((size_t)N * 128);
  size_t Q1_off     = take((size_t)N * 128 * 2);
  size_t Q2_off     = take((size_t)N * 128 * 2);
  size_t X1_off     = take((size_t)N * 128 * 2);
  size_t X2_off     = take((size_t)N * 128 * 2);
  size_t G_off      = take((size_t)N * 256 * 2);

  int*    cnt     = (int*)(wsb + cnt_off);
  float*  stats   = (float*)(wsb + stats_off);
  int*    row_off = (int*)(wsb + rowoff_off);
  int*    cursor  = (int*)(wsb + cursor_off);
  int*    bsum    = (int*)(wsb + bsum_off);
  int*    bcur    = (int*)(wsb + bcur_off);
  int*    esrc    = (int*)(wsb + esrc_off);
  uint2*  ebuf    = (uint2*)(wsb + ebuf_off);
  ushort16* wpool = (ushort16*)(wsb + wpool_off);
  ushort16* h_f   = (ushort16*)(wsb + hf_off);
  ushort16* sv_f  = (ushort16*)(wsb + svf_off);
  ushort16* cat_h = (ushort16*)(wsb + cath_off);
  ushort16* cat_sv= (ushort16*)(wsb + catsv_off);
  uchar*    K8_1  = (uchar*)(wsb + K81_off);
  uchar*    V8_1  = (uchar*)(wsb + V81_off);
  uchar*    K8_2  = (uchar*)(wsb + K82_off);
  uchar*    V8_2  = (uchar*)(wsb + V82_off);
  ushort16* Q1    = (ushort16*)(wsb + Q1_off);
  ushort16* Q2    = (ushort16*)(wsb + Q2_off);
  ushort16* Xb1   = (ushort16*)(wsb + X1_off);
  ushort16* Xb2   = (ushort16*)(wsb + X2_off);
  ushort16* Gb16  = (ushort16*)(wsb + G_off);

  ushort16* Wq_sv = wpool + 0 * 16384;
  ushort16* Wk_sv = wpool + 1 * 16384;
  ushort16* Wv_sv = wpool + 2 * 16384;
  ushort16* Wq_cv = wpool + 3 * 16384;
  ushort16* Wk_cv = wpool + 4 * 16384;
  ushort16* Wv_cv = wpool + 5 * 16384;
  ushort16* Wq_sh = wpool + 6 * 16384;
  ushort16* Wk_sh = wpool + 7 * 16384;
  ushort16* Wv_sh = wpool + 8 * 16384;
  ushort16* Wgb   = wpool + 147456;
  ushort16* Wob   = wpool + 180224;
  ushort16* Wohb  = wpool + 212992;
  ushort16* W1b   = wpool + 245760;
  ushort16* W2b   = wpool + 278528;
  ushort16* W1hb  = wpool + 311296;
  ushort16* W2hb  = wpool + 344064;

  const float* bo   = (const float*)d_in[14];
  const float* bo_h = (const float*)d_in[16];
  const float* b1   = (const float*)d_in[18];
  const float* b2   = (const float*)d_in[20];
  const float* b1h  = (const float*)d_in[22];
  const float* b2h  = (const float*)d_in[24];
  const float* bg1  = (const float*)d_in[26];
  const float* bg2  = (const float*)d_in[28];
  const float* gbn1  = (const float*)d_in[29];
  const float* bbn1  = (const float*)d_in[30];
  const float* gbn2  = (const float*)d_in[31];
  const float* bbn2  = (const float*)d_in[32];
  const float* gbn1h = (const float*)d_in[33];
  const float* bbn1h = (const float*)d_in[34];
  const float* gbn2h = (const float*)d_in[35];
  const float* bbn2h = (const float*)d_in[36];

  float* out_h  = (float*)d_out;
  float* out_sv = out_h + (size_t)N * 128;

  (void)hipMemsetAsync(wsb, 0, stats_off + 4 * 256 * 4, stream);

  WConv wc;
  {
    auto set = [&](int i, int din, int din2, size_t dstoff, int KD, int MD){
      wc.e[i].s  = (const float*)d_in[din];
      wc.e[i].s2 = (din2 >= 0) ? (const float*)d_in[din2] : nullptr;
      wc.e[i].d  = wpool + dstoff;
      wc.e[i].KD = KD; wc.e[i].MD = MD;
      wc.e[i].nfrag = KD * MD / 8;
    };
    for (int i = 0; i < 9; i++) set(i, 4 + i, -1, (size_t)i * 16384, 128, 128);
    set(9,  25, 27, 147456, 128, 256);
    set(10, 13, -1, 180224, 256, 128);
    set(11, 15, -1, 212992, 256, 128);
    set(12, 17, -1, 245760, 128, 256);
    set(13, 19, -1, 278528, 256, 128);
    set(14, 21, -1, 311296, 128, 256);
    set(15, 23, -1, 344064, 256, 128);
  }
  conv_w_k<<<dim3(16, 16), 256, 0, stream>>>(wc);

  int nelem = N * 128;
  conv2_k<<<dim3((nelem / 4 + 255) / 256, 2), 256, 0, stream>>>(h, sv, h_f, sv_f, nelem);

  // bucket params: B <= 128 buckets of 2^shift dst values
  int shift = 9;
  while ((((N - 1) >> shift) + 1) > 128) shift++;
  const int B = ((N - 1) >> shift) + 1;

  const int NB = (N + 1023) / 1024;
  hist_k<<<2048, 256, 0, stream>>>(dst, cnt, E);
  scan_part_k<<<NB, 256, 0, stream>>>(cnt, bsum, N);
  scan_top_k<<<1, 64, 0, stream>>>(bsum, NB);
  scan_out_k<<<NB, 256, 0, stream>>>(cnt, bsum, row_off, cursor, bcur, N, E, shift);
  bin_k<<<(E + BIN_TILE - 1) / BIN_TILE, BIN_TB, 0, stream>>>(src, dst, bcur, ebuf, E, shift, B);
  bfill_k<<<B, 512, 0, stream>>>(ebuf, row_off, cursor, esrc, shift, N);

  const int GB = (N + 63) / 64;
  const int AB = (N + 3) / 4;
  const int T4 = nelem / 4;
  const int APB = (T4 + 255) / 256;
  const float invN = 1.f / (float)N;

  // h-branch attention pair
  gemm_qkv_k<<<GB, 256, 0, stream>>>(h_f, h_f, Wq_sv, Wk_sv, Wv_sv, Q1, K8_1, V8_1, N);
  gemm_qkv_k<<<GB, 256, 0, stream>>>(h_f, sv_f, Wq_cv, Wk_cv, Wv_cv, Q2, K8_2, V8_2, N);
  attn2_k<<<AB, 256, 0, stream>>>(Q1, Q2, K8_1, V8_1, K8_2, V8_2, row_off, esrc, cat_h, N);
  // sv-branch attention pair
  gemm_qkv_k<<<GB, 256, 0, stream>>>(sv_f, sv_f, Wq_sh, Wk_sh, Wv_sh, Q1, K8_1, V8_1, N);
  gemm_qkv_k<<<GB, 256, 0, stream>>>(sv_f, h_f, Wq_cv, Wk_cv, Wv_cv, Q2, K8_2, V8_2, N);
  attn2_k<<<AB, 256, 0, stream>>>(Q1, Q2, K8_1, V8_1, K8_2, V8_2, row_off, esrc, cat_sv, N);

  // ---- h branch ----
  gemm_k<256,128,3,0,1,256><<<GB, 256, 0, stream>>>(cat_h, Wob, bo, nullptr, h_f, nullptr,
      nullptr, nullptr, nullptr, nullptr, nullptr, nullptr, Xb1, stats, N, invN);
  gemm_k<128,256,1,1,0,256><<<GB, 256, 0, stream>>>(Xb1, W1b, b1, nullptr, nullptr, nullptr,
      nullptr, nullptr, nullptr, stats, gbn1, bbn1, cat_h, nullptr, N, invN);
  gemm_k<256,128,5,0,1,256><<<GB, 256, 0, stream>>>(cat_h, W2b, b2, nullptr, Xb1, nullptr,
      stats, gbn1, bbn1, nullptr, nullptr, nullptr, Xb2, stats + 256, N, invN);
  bn_apply_k<<<APB, 256, 0, stream>>>(Xb2, stats + 256, gbn2, bbn2, out_h, T4, invN);

  // ---- sv branch ----
  gemm_k<128,256,2,0,0,256><<<GB, 256, 0, stream>>>(h_f, Wgb, bg1, bg2, nullptr, nullptr,
      nullptr, nullptr, nullptr, nullptr, nullptr, nullptr, Gb16, nullptr, N, invN);
  gemm_k<256,128,4,0,1,256><<<GB, 256, 0, stream>>>(cat_sv, Wohb, bo_h, nullptr, sv_f, Gb16,
      nullptr, nullptr, nullptr, nullptr, nullptr, nullptr, Xb1, stats + 512, N, invN);
  gemm_k<128,256,1,1,0,256><<<GB, 256, 0, stream>>>(Xb1, W1hb, b1h, nullptr, nullptr, nullptr,
      nullptr, nullptr, nullptr, stats + 512, gbn1h, bbn1h, cat_sv, nullptr, N, invN);
  gemm_k<256,128,6,0,1,256><<<GB, 256, 0, stream>>>(cat_sv, W2hb, b2h, nullptr, Xb1, Gb16 + 128,
      stats + 512, gbn1h, bbn1h, nullptr, nullptr, nullptr, Xb2, stats + 768, N, invN);
  bn_apply_k<<<APB, 256, 0, stream>>>(Xb2, stats + 768, gbn2h, bbn2h, out_sv, T4, invN);
}

// Round 2
// 874.661 us; speedup vs baseline: 1.0375x; 1.0375x over previous
//
#include <hip/hip_runtime.h>

typedef _Float16 f16x8 __attribute__((ext_vector_type(8)));
typedef _Float16 f16x2 __attribute__((ext_vector_type(2)));
typedef __fp16 fp16x2_raw __attribute__((ext_vector_type(2)));
typedef float f32x4 __attribute__((ext_vector_type(4)));
typedef float f32x2 __attribute__((ext_vector_type(2)));
typedef unsigned int uint32;
typedef unsigned short ushort16;
typedef unsigned char uchar;

#define EPS_BN 1e-5f

__device__ __forceinline__ uint32 pk16(float a, float b){
  fp16x2_raw h = __builtin_amdgcn_cvt_pkrtz(a, b);
  return *(uint32*)&h;
}
__device__ __forceinline__ ushort16 f2h(float f){
  _Float16 h = (_Float16)f;
  union { _Float16 h; ushort16 u; } c; c.h = h; return c.u;
}
__device__ __forceinline__ uchar f2fp8(float f){
  uint32 p = __builtin_amdgcn_cvt_pk_fp8_f32(f, f, 0, false);
  return (uchar)(p & 0xff);
}
__device__ __forceinline__ f32x2 fp8pair_lo(uint32 w){
  return __builtin_amdgcn_cvt_pk_f32_fp8(w, false);
}
__device__ __forceinline__ f32x2 fp8pair_hi(uint32 w){
  return __builtin_amdgcn_cvt_pk_f32_fp8(w, true);
}

// ---------------- weight conversion: f32 row-major -> f16 MFMA-fragment-linear ----------------
struct WEnt { const float* s; const float* s2; ushort16* d; int KD, MD, nfrag; };
struct WConv { WEnt e[16]; };

__global__ __launch_bounds__(256) void conv_w_k(WConv a){
  WEnt t = a.e[blockIdx.y];
  int fid = blockIdx.x * 256 + threadIdx.x;
  if (fid >= t.nfrag) return;
  int lane = fid & 63, sm = fid >> 6;
  int MT = t.MD >> 4;
  int s = sm / MT, m = sm - s * MT;
  int row = m * 16 + (lane & 15);
  int col = s * 32 + (lane >> 4) * 8;
  const float* sp = t.s;
  if (t.s2 && row >= 128){ sp = t.s2; row -= 128; }
  const float* p = sp + (size_t)row * t.KD + col;
  uint4 o;
  o.x = pk16(p[0], p[1]); o.y = pk16(p[2], p[3]);
  o.z = pk16(p[4], p[5]); o.w = pk16(p[6], p[7]);
  *(uint4*)(t.d + (size_t)fid * 8) = o;
}

__global__ __launch_bounds__(256) void conv2_k(const float* __restrict__ a, const float* __restrict__ b,
                                               ushort16* __restrict__ da, ushort16* __restrict__ db, int n){
  const float* s = blockIdx.y ? b : a;
  ushort16* d = blockIdx.y ? db : da;
  int i = (blockIdx.x * 256 + threadIdx.x) * 4;
  if (i >= n) return;
  float4 v = *(const float4*)(s + i);
  uint2 p;
  p.x = pk16(v.x, v.y);
  p.y = pk16(v.z, v.w);
  *(uint2*)(d + i) = p;
}

// ---------------- CSR build ----------------
__global__ void hist_k(const int* __restrict__ dst, int* __restrict__ cnt, int E){
  int i = blockIdx.x * blockDim.x + threadIdx.x;
  int stride = gridDim.x * blockDim.x;
  for (; i < E; i += stride) atomicAdd(&cnt[dst[i]], 1);
}

__global__ __launch_bounds__(256) void scan_part_k(const int* __restrict__ cnt, int* __restrict__ bsum, int N){
  int tid = threadIdx.x, lane = tid & 63, wv = tid >> 6;
  int base = blockIdx.x * 1024 + tid * 4;
  int ts = 0;
  #pragma unroll
  for (int j = 0; j < 4; j++) if (base + j < N) ts += cnt[base + j];
  #pragma unroll
  for (int d = 1; d < 64; d <<= 1) ts += __shfl_xor(ts, d);
  __shared__ int wt[4];
  if (lane == 0) wt[wv] = ts;
  __syncthreads();
  if (tid == 0) bsum[blockIdx.x] = wt[0] + wt[1] + wt[2] + wt[3];
}

__global__ __launch_bounds__(64) void scan_top_k(int* __restrict__ bsum, int nb){
  int tid = threadIdx.x;
  int v = (tid < nb) ? bsum[tid] : 0;
  int inc = v;
  #pragma unroll
  for (int d = 1; d < 64; d <<= 1){
    int t = __shfl_up(inc, d);
    if (tid >= d) inc += t;
  }
  if (tid < nb) bsum[tid] = inc - v;
}

// stage 3: write row_off/cursor (+ per-bucket cursors for the binned fill)
__global__ __launch_bounds__(256) void scan_out_k(const int* __restrict__ cnt, const int* __restrict__ bsum,
                                                  int* __restrict__ row_off, int* __restrict__ cursor,
                                                  int* __restrict__ bcur,
                                                  int N, int E, int shift){
  int tid = threadIdx.x, lane = tid & 63, wv = tid >> 6;
  int base = blockIdx.x * 1024 + tid * 4;
  int c[4]; int ts = 0;
  #pragma unroll
  for (int j = 0; j < 4; j++){ c[j] = (base + j < N) ? cnt[base + j] : 0; ts += c[j]; }
  int inc = ts;
  #pragma unroll
  for (int d = 1; d < 64; d <<= 1){
    int t = __shfl_up(inc, d);
    if (lane >= d) inc += t;
  }
  int wexcl = inc - ts;
  __shared__ int wt[4];
  if (lane == 63) wt[wv] = inc;
  __syncthreads();
  int woff = 0;
  for (int w = 0; w < 4; w++) if (w < wv) woff += wt[w];
  int off = bsum[blockIdx.x] + woff + wexcl;
  int mask = (1 << shift) - 1;
  #pragma unroll
  for (int j = 0; j < 4; j++){
    int d = base + j;
    if (d < N){
      row_off[d] = off; cursor[d] = off;
      if ((d & mask) == 0) bcur[d >> shift] = off;
      off += c[j];
    }
  }
  if (blockIdx.x == 0 && tid == 0) row_off[N] = E;
}

// ---------------- bucketed fill: pass 1, LDS-binned grouping by dst bucket ----------------
#define BIN_TB 512
#define BIN_TILE 4096
__global__ __launch_bounds__(512) void bin_k(const int* __restrict__ src, const int* __restrict__ dst,
                                             int* __restrict__ bcur, uint2* __restrict__ ebuf,
                                             int E, int shift, int B){
  __shared__ int lhist[128];
  __shared__ int lstart[128];
  __shared__ int gbase[128];
  __shared__ uint2 lpair[BIN_TILE];
  int tid = threadIdx.x;
  int base = blockIdx.x * BIN_TILE;
  int cnt = E - base; if (cnt > BIN_TILE) cnt = BIN_TILE;
  if (tid < 128) lhist[tid] = 0;
  __syncthreads();
  int myb[8], myrank[8];
  uint2 myp[8];
  int nmine = 0;
  #pragma unroll
  for (int j = 0; j < 8; j++){
    int i = tid + j * BIN_TB;
    if (i < cnt){
      int s = src[base + i], d = dst[base + i];
      int b = d >> shift;
      myp[nmine] = make_uint2((uint32)s, (uint32)d);
      myb[nmine] = b;
      myrank[nmine] = atomicAdd(&lhist[b], 1);
      nmine++;
    }
  }
  __syncthreads();
  if (tid == 0){
    int run = 0;
    for (int b = 0; b < B; b++){ lstart[b] = run; run += lhist[b]; }
  }
  __syncthreads();
  if (tid < B) gbase[tid] = atomicAdd(&bcur[tid], lhist[tid]);
  for (int j = 0; j < nmine; j++){
    lpair[lstart[myb[j]] + myrank[j]] = myp[j];
  }
  __syncthreads();
  for (int i = tid; i < cnt; i += BIN_TB){
    uint2 p = lpair[i];
    int b = (int)(p.y >> shift);
    ebuf[gbase[b] + (i - lstart[b])] = p;
  }
}

// ---------------- bucketed fill: pass 2, bucket-local cursor scatter ----------------
__global__ __launch_bounds__(512) void bfill_k(const uint2* __restrict__ ebuf, const int* __restrict__ row_off,
                                               int* __restrict__ cursor, int* __restrict__ esrc,
                                               int shift, int N){
  int b = blockIdx.x;
  int d0 = b << shift;
  int d1 = (b + 1) << shift; if (d1 > N) d1 = N;
  if (d0 >= N) return;
  int e0 = row_off[d0], e1 = row_off[d1];
  for (int i = e0 + (int)threadIdx.x; i < e1; i += 512){
    uint2 p = ebuf[i];
    int pos = atomicAdd(&cursor[p.y], 1);
    esrc[pos] = (int)p.x;
  }
}

// ---------------- fused QKV projection, LDS-staged coalesced stores ----------------
// K and V are stored interleaved per node: KV8[s*256 + 0..127]=K row, [128..255]=V row
__global__ __launch_bounds__(256) void gemm_qkv_k(
    const ushort16* __restrict__ Xq, const ushort16* __restrict__ Xkv,
    const ushort16* __restrict__ Wq, const ushort16* __restrict__ Wk, const ushort16* __restrict__ Wv,
    ushort16* __restrict__ Qo, uchar* __restrict__ KV8, int N)
{
  __shared__ _Float16 Qs[4][16 * 136];
  __shared__ uchar Ks[4][16 * 136];
  __shared__ uchar Vs[4][16 * 136];
  int lane = threadIdx.x & 63, wv = threadIdx.x >> 6;
  int l15 = lane & 15, kq = lane >> 4;
  int rowbase = (blockIdx.x * 4 + wv) * 16;
  int row = rowbase + l15;
  int rc = row < N ? row : N - 1;
  const f16x8* aq = (const f16x8*)(Xq + (size_t)rc * 128 + kq * 8);
  const f16x8* ak = (const f16x8*)(Xkv + (size_t)rc * 128 + kq * 8);
  f16x8 Aq[4], Ak[4];
  #pragma unroll
  for (int s = 0; s < 4; s++){ Aq[s] = aq[s * 4]; Ak[s] = ak[s * 4]; }
  const f16x8* Wqf = (const f16x8*)Wq;
  const f16x8* Wkf = (const f16x8*)Wk;
  const f16x8* Wvf = (const f16x8*)Wv;
  f32x4 q[8], k[8], v[8];
  #pragma unroll
  for (int m = 0; m < 8; m++){ q[m] = (f32x4)(0.f); k[m] = (f32x4)(0.f); v[m] = (f32x4)(0.f); }
  #pragma unroll
  for (int s = 0; s < 4; s++){
    #pragma unroll
    for (int m = 0; m < 8; m++){
      int fi = (s * 8 + m) * 64 + lane;
      q[m] = __builtin_amdgcn_mfma_f32_16x16x32_f16(Aq[s], Wqf[fi], q[m], 0, 0, 0);
      k[m] = __builtin_amdgcn_mfma_f32_16x16x32_f16(Ak[s], Wkf[fi], k[m], 0, 0, 0);
      v[m] = __builtin_amdgcn_mfma_f32_16x16x32_f16(Ak[s], Wvf[fi], v[m], 0, 0, 0);
    }
  }
  #pragma unroll
  for (int m = 0; m < 8; m++){
    int col = m * 16 + l15;
    #pragma unroll
    for (int r = 0; r < 4; r++){
      int lrow = kq * 4 + r;
      Qs[wv][lrow * 136 + col] = (_Float16)q[m][r];
      Ks[wv][lrow * 136 + col] = f2fp8(k[m][r]);
      Vs[wv][lrow * 136 + col] = f2fp8(v[m][r]);
    }
  }
  #pragma unroll
  for (int p = 0; p < 4; p++){
    int lrow = p * 4 + (lane >> 4);
    int rr = rowbase + lrow;
    int col8 = l15 * 8;
    if (rr < N){
      uint4 qv = *(uint4*)&Qs[wv][lrow * 136 + col8];
      *(uint4*)(Qo + (size_t)rr * 128 + col8) = qv;
      uint2 kv = *(uint2*)&Ks[wv][lrow * 136 + col8];
      *(uint2*)(KV8 + (size_t)rr * 256 + col8) = kv;
      uint2 vv = *(uint2*)&Vs[wv][lrow * 136 + col8];
      *(uint2*)(KV8 + (size_t)rr * 256 + 128 + col8) = vv;
    }
  }
}

// ---------------- generic GEMM, swizzled W, f16 in/out, LDS-staged stores ----------------
// EPI: 1=relu, 2=sigmoid, 3=+res(f16), 4=gate w/ res(f16), 5=+BN(res), 6=gate w/ BN(res)
// ABN=1: apply BN to A on load. ST=1: accumulate column stats.
template<int KD, int MD, int EPI, int ABN, int ST, int GS>
__global__ __launch_bounds__(256) void gemm_k(
    const ushort16* __restrict__ X, const ushort16* __restrict__ W,
    const float* __restrict__ bias, const float* __restrict__ bias2,
    const ushort16* __restrict__ resb, const ushort16* __restrict__ gatep,
    const float* __restrict__ rstats, const float* __restrict__ rg, const float* __restrict__ rb,
    const float* __restrict__ astats, const float* __restrict__ ag, const float* __restrict__ ab,
    ushort16* __restrict__ outb, float* __restrict__ stats_out, int N, float invN)
{
  constexpr int KS = KD / 32;
  constexpr int MT = MD / 16;
  constexpr int LSTR = MD + 8;
  __shared__ _Float16 Os[4][16 * LSTR];
  int lane = threadIdx.x & 63, wv = threadIdx.x >> 6;
  int l15 = lane & 15, kq = lane >> 4;
  int rowbase = (blockIdx.x * 4 + wv) * 16;
  int row = rowbase + l15;
  int rc = row < N ? row : N - 1;
  const f16x8* ap = (const f16x8*)(X + (size_t)rc * KD + kq * 8);
  f16x8 a[KS];
  #pragma unroll
  for (int s = 0; s < KS; s++) a[s] = ap[s * 4];
  if constexpr (ABN){
    #pragma unroll
    for (int s = 0; s < KS; s++){
      #pragma unroll
      for (int j = 0; j < 8; j++){
        int c = s * 32 + kq * 8 + j;
        float mm = astats[c] * invN;
        float var = astats[128 + c] * invN - mm * mm;
        float rs = rsqrtf(var + EPS_BN);
        float scc = rs * ag[c];
        float shh = ab[c] - mm * scc;
        a[s][j] = (_Float16)((float)a[s][j] * scc + shh);
      }
    }
  }
  const f16x8* Wf = (const f16x8*)W;
  f32x4 acc[MT];
  #pragma unroll
  for (int m = 0; m < MT; m++) acc[m] = (f32x4)(0.f);
  #pragma unroll
  for (int s = 0; s < KS; s++){
    #pragma unroll
    for (int m = 0; m < MT; m++){
      acc[m] = __builtin_amdgcn_mfma_f32_16x16x32_f16(a[s], Wf[(s * MT + m) * 64 + lane], acc[m], 0, 0, 0);
    }
  }
  float ps[MT], ps2[MT];
  if constexpr (ST){
    #pragma unroll
    for (int m = 0; m < MT; m++){ ps[m] = 0.f; ps2[m] = 0.f; }
  }
  int r0 = rowbase + kq * 4;
  #pragma unroll
  for (int m = 0; m < MT; m++){
    int col = m * 16 + l15;
    float bv;
    if (bias2 && col >= 128) bv = bias2[col - 128];
    else bv = bias[col];
    float sc = 0.f, sh = 0.f;
    if constexpr (EPI == 5 || EPI == 6){
      float mm = rstats[col] * invN;
      float var = rstats[128 + col] * invN - mm * mm;
      float rs = rsqrtf(var + EPS_BN);
      sc = rs * rg[col]; sh = rb[col] - mm * sc;
    }
    #pragma unroll
    for (int r = 0; r < 4; r++){
      int rr = r0 + r;
      float v;
      {
        int rrc = rr < N ? rr : N - 1;
        v = acc[m][r] + bv;
        if constexpr (EPI == 1) v = fmaxf(v, 0.f);
        if constexpr (EPI == 2) v = 1.f / (1.f + __expf(-v));
        if constexpr (EPI == 3){
          union { ushort16 u; _Float16 h; } cv; cv.u = resb[(size_t)rrc * 128 + col];
          v += (float)cv.h;
        }
        if constexpr (EPI == 5){
          union { ushort16 u; _Float16 h; } cv; cv.u = resb[(size_t)rrc * 128 + col];
          v += (float)cv.h * sc + sh;
        }
        if constexpr (EPI == 4 || EPI == 6){
          union { ushort16 u; _Float16 h; } gv; gv.u = gatep[(size_t)rrc * GS + col];
          union { ushort16 u; _Float16 h; } cv; cv.u = resb[(size_t)rrc * 128 + col];
          float g = (float)gv.h;
          float rv = (float)cv.h;
          if constexpr (EPI == 6) rv = rv * sc + sh;
          v = (1.f - g) * rv + g * v;
        }
      }
      Os[wv][(kq * 4 + r) * LSTR + col] = (_Float16)v;
      if constexpr (ST){
        if (rr < N){ ps[m] += v; ps2[m] += v * v; }
      }
    }
  }
  if constexpr (MD == 128){
    #pragma unroll
    for (int p = 0; p < 4; p++){
      int lrow = p * 4 + (lane >> 4);
      int rr = rowbase + lrow;
      int col8 = l15 * 8;
      if (rr < N){
        uint4 ov = *(uint4*)&Os[wv][lrow * LSTR + col8];
        *(uint4*)(outb + (size_t)rr * MD + col8) = ov;
      }
    }
  } else {
    #pragma unroll
    for (int p = 0; p < 8; p++){
      int lrow = p * 2 + (lane >> 5);
      int rr = rowbase + lrow;
      int col8 = (lane & 31) * 8;
      if (rr < N){
        uint4 ov = *(uint4*)&Os[wv][lrow * LSTR + col8];
        *(uint4*)(outb + (size_t)rr * MD + col8) = ov;
      }
    }
  }
  if constexpr (ST){
    __shared__ float sst[4][128];
    __shared__ float sst2[4][128];
    #pragma unroll
    for (int m = 0; m < MT; m++){
      float s = ps[m], s2 = ps2[m];
      s  += __shfl_xor(s, 16);  s  += __shfl_xor(s, 32);
      s2 += __shfl_xor(s2, 16); s2 += __shfl_xor(s2, 32);
      if (lane < 16){ sst[wv][m * 16 + l15] = s; sst2[wv][m * 16 + l15] = s2; }
    }
    __syncthreads();
    int tid = threadIdx.x;
    if (tid < 128){
      atomicAdd(&stats_out[tid], sst[0][tid] + sst[1][tid] + sst[2][tid] + sst[3][tid]);
    } else {
      int c = tid - 128;
      atomicAdd(&stats_out[tid], sst2[0][c] + sst2[1][c] + sst2[2][c] + sst2[3][c]);
    }
  }
}

// ---------------- fused QUAD attention (all 4 edge-attentions in one pass) ----------------
// Latency-bound kernel: one esrc load feeds 8 fp8 K/V gathers (interleaved KV
// layout, 256B/node) -> 2x memory-level parallelism vs the old dual kernel and
// shared loop/address/esrc overhead.
__global__ __launch_bounds__(256) void attn4_k(
    const ushort16* __restrict__ Qa, const ushort16* __restrict__ Qb,
    const ushort16* __restrict__ Qc, const ushort16* __restrict__ Qd,
    const uchar* __restrict__ KVa, const uchar* __restrict__ KVb,
    const uchar* __restrict__ KVc, const uchar* __restrict__ KVd,
    const int* __restrict__ row_off, const int* __restrict__ esrc,
    ushort16* __restrict__ cat_h, ushort16* __restrict__ cat_sv, int N)
{
  int wv = threadIdx.x >> 6, lane = threadIdx.x & 63;
  int n = blockIdx.x * 4 + wv;
  if (n >= N) return;
  int h = lane >> 5, j = lane & 31;
  uint32 j4 = (uint32)j * 4u;
  const float QS = 0.25f * 1.44269504088896f; // 1/sqrt(DH) * log2(e)
  const float CL = 7.21347520444482f;          // 5 * log2(e)
  const ushort16* Qp[4] = {Qa, Qb, Qc, Qd};
  const uchar* KVp[4] = {KVa, KVb, KVc, KVd};
  f32x2 q01[4], q23[4];
  #pragma unroll
  for (int t = 0; t < 4; t++){
    uint2 u = *(const uint2*)(Qp[t] + (size_t)n * 128 + j4);
    f16x2 t0 = *(f16x2*)&u.x, t1 = *(f16x2*)&u.y;
    q01[t].x = (float)t0.x * QS; q01[t].y = (float)t0.y * QS;
    q23[t].x = (float)t1.x * QS; q23[t].y = (float)t1.y * QS;
  }
  int e0 = row_off[n], e1 = row_off[n + 1];
  int itmax = (e1 - e0 + 1) >> 1;
  f32x2 ac01[4], ac23[4];
  #pragma unroll
  for (int t = 0; t < 4; t++){ ac01[t] = (f32x2)(0.f); ac23[t] = (f32x2)(0.f); }
  f32x2 z01 = (f32x2)(0.f), z23 = (f32x2)(0.f);
  int e = e0 + h;
  int s = (e < e1) ? esrc[e] : -1;
  uint32 off = ((uint32)(s < 0 ? 0 : s) << 8) + j4;
  uint32 kc_[4], vc_[4];
  #pragma unroll
  for (int t = 0; t < 4; t++){
    kc_[t] = *(const uint32*)(KVp[t] + off);
    vc_[t] = *(const uint32*)(KVp[t] + off + 128);
  }
  for (int it = 0; it < itmax; ++it){
    int e2 = e + 2;
    int s2 = (e2 < e1) ? esrc[e2] : -1;
    uint32 off2 = ((uint32)(s2 < 0 ? 0 : s2) << 8) + j4;
    uint32 kn_[4], vn_[4];
    #pragma unroll
    for (int t = 0; t < 4; t++){
      kn_[t] = *(const uint32*)(KVp[t] + off2);
      vn_[t] = *(const uint32*)(KVp[t] + off2 + 128);
    }
    if (s >= 0){
      float d[4];
      #pragma unroll
      for (int t = 0; t < 4; t++){
        f32x2 k01 = fp8pair_lo(kc_[t]), k23 = fp8pair_hi(kc_[t]);
        f32x2 dd = k01 * q01[t] + k23 * q23[t];
        d[t] = dd.x + dd.y;
      }
      #pragma unroll
      for (int t = 0; t < 4; t++){
        d[t] += __shfl_xor(d[t], 1);
        d[t] += __shfl_xor(d[t], 2);
      }
      float sc4[4];
      #pragma unroll
      for (int t = 0; t < 4; t++)
        sc4[t] = __builtin_amdgcn_exp2f(__builtin_amdgcn_fmed3f(d[t], -CL, CL));
      #pragma unroll
      for (int t = 0; t < 4; t++){
        f32x2 v01 = fp8pair_lo(vc_[t]), v23 = fp8pair_hi(vc_[t]);
        f32x2 sv; sv.x = sc4[t]; sv.y = sc4[t];
        ac01[t] += sv * v01;
        ac23[t] += sv * v23;
      }
      z01.x += sc4[0]; z01.y += sc4[1];
      z23.x += sc4[2]; z23.y += sc4[3];
    }
    e = e2; s = s2;
    #pragma unroll
    for (int t = 0; t < 4; t++){ kc_[t] = kn_[t]; vc_[t] = vn_[t]; }
  }
  // cross-half reduce (edge e vs e+1 halves)
  #pragma unroll
  for (int t = 0; t < 4; t++){
    f32x2 x;
    x.x = __shfl_xor(ac01[t].x, 32); x.y = __shfl_xor(ac01[t].y, 32); ac01[t] += x;
    x.x = __shfl_xor(ac23[t].x, 32); x.y = __shfl_xor(ac23[t].y, 32); ac23[t] += x;
  }
  {
    f32x2 x;
    x.x = __shfl_xor(z01.x, 32); x.y = __shfl_xor(z01.y, 32); z01 += x;
    x.x = __shfl_xor(z23.x, 32); x.y = __shfl_xor(z23.y, 32); z23 += x;
  }
  size_t nbh = (size_t)n * 256 + j4;
  uint2 o;
  if (h == 0){
    float rz = __builtin_amdgcn_rcpf(z01.x);
    o.x = pk16(ac01[0].x * rz, ac01[0].y * rz);
    o.y = pk16(ac23[0].x * rz, ac23[0].y * rz);
    *(uint2*)(cat_h + nbh) = o;
    rz = __builtin_amdgcn_rcpf(z23.x);
    o.x = pk16(ac01[2].x * rz, ac01[2].y * rz);
    o.y = pk16(ac23[2].x * rz, ac23[2].y * rz);
    *(uint2*)(cat_sv + nbh) = o;
  } else {
    float rz = __builtin_amdgcn_rcpf(z01.y);
    o.x = pk16(ac01[1].x * rz, ac01[1].y * rz);
    o.y = pk16(ac23[1].x * rz, ac23[1].y * rz);
    *(uint2*)(cat_h + nbh + 128) = o;
    rz = __builtin_amdgcn_rcpf(z23.y);
    o.x = pk16(ac01[3].x * rz, ac01[3].y * rz);
    o.y = pk16(ac23[3].x * rz, ac23[3].y * rz);
    *(uint2*)(cat_sv + nbh + 128) = o;
  }
}

// ---------------- BatchNorm apply (f16 in, f32 out) ----------------
__global__ __launch_bounds__(256) void bn_apply_k(
    const ushort16* __restrict__ x, const float* __restrict__ stats,
    const float* __restrict__ gamma, const float* __restrict__ beta,
    float* __restrict__ outf, int total4, float invN)
{
  int i = blockIdx.x * 256 + threadIdx.x;
  if (i >= total4) return;
  uint2 xp = *(const uint2*)(x + (size_t)i * 4);
  f16x2 x01 = *(f16x2*)&xp.x, x23 = *(f16x2*)&xp.y;
  float xv[4] = {(float)x01.x, (float)x01.y, (float)x23.x, (float)x23.y};
  int c0 = (i * 4) & 127;
  float o[4];
  #pragma unroll
  for (int j = 0; j < 4; j++){
    int c = c0 + j;
    float m = stats[c] * invN;
    float var = stats[128 + c] * invN - m * m;
    float rstd = rsqrtf(var + EPS_BN);
    o[j] = (xv[j] - m) * rstd * gamma[c] + beta[c];
  }
  *(float4*)(outf + (size_t)i * 4) = make_float4(o[0], o[1], o[2], o[3]);
}

// ---------------- host ----------------
extern "C" void kernel_launch(void* const* d_in, const int* in_sizes, int n_in,
                              void* d_out, int out_size, void* d_ws, size_t ws_size,
                              hipStream_t stream) {
  const float* h   = (const float*)d_in[0];
  const float* sv  = (const float*)d_in[1];
  const int* src   = (const int*)d_in[2];
  const int* dst   = (const int*)d_in[3];
  const int N = in_sizes[0] / 128;
  const int E = in_sizes[2];

  char* wsb = (char*)d_ws;
  size_t o = 0;
  auto take = [&](size_t bytes)->size_t{
    size_t r = o;
    o = (o + bytes + 255) & ~(size_t)255;
    return r;
  };
  size_t ebuf_bytes = (size_t)E * 8;
  if (ebuf_bytes < (size_t)N * 256) ebuf_bytes = (size_t)N * 256; // doubles as KV3
  size_t cnt_off    = take((size_t)N * 4);
  size_t stats_off  = take(4 * 256 * 4);
  size_t rowoff_off = take((size_t)(N + 1) * 4);
  size_t cursor_off = take((size_t)N * 4);
  size_t bsum_off   = take(256 * 4);
  size_t bcur_off   = take(128 * 4);
  size_t esrc_off   = take((size_t)E * 4);
  size_t ebuf_off   = take(ebuf_bytes);
  size_t wpool_off  = take((size_t)376832 * 2);
  size_t hf_off     = take((size_t)N * 128 * 2);
  size_t svf_off    = take((size_t)N * 128 * 2);
  size_t cath_off   = take((size_t)N * 256 * 2);
  size_t catsv_off  = take((size_t)N * 256 * 2);
  size_t K81_off    = take((size_t)N * 128);
  size_t V81_off    = take((size_t)N * 128);
  size_t K82_off    = take((size_t)N * 128);
  size_t V82_off    = take((size_t)N * 128);
  size_t Q1_off     = take((size_t)N * 128 * 2);
  size_t Q2_off     = take((size_t)N * 128 * 2);
  size_t X1_off     = take((size_t)N * 128 * 2);
  size_t X2_off     = take((size_t)N * 128 * 2);
  size_t G_off      = take((size_t)N * 256 * 2);

  int*    cnt     = (int*)(wsb + cnt_off);
  float*  stats   = (float*)(wsb + stats_off);
  int*    row_off = (int*)(wsb + rowoff_off);
  int*    cursor  = (int*)(wsb + cursor_off);
  int*    bsum    = (int*)(wsb + bsum_off);
  int*    bcur    = (int*)(wsb + bcur_off);
  int*    esrc    = (int*)(wsb + esrc_off);
  uint2*  ebuf    = (uint2*)(wsb + ebuf_off);
  ushort16* wpool = (ushort16*)(wsb + wpool_off);
  ushort16* h_f   = (ushort16*)(wsb + hf_off);
  ushort16* sv_f  = (ushort16*)(wsb + svf_off);
  ushort16* cat_h = (ushort16*)(wsb + cath_off);
  ushort16* cat_sv= (ushort16*)(wsb + catsv_off);
  ushort16* Q1    = (ushort16*)(wsb + Q1_off);
  ushort16* Q2    = (ushort16*)(wsb + Q2_off);
  ushort16* Xb1   = (ushort16*)(wsb + X1_off);
  ushort16* Xb2   = (ushort16*)(wsb + X2_off);
  ushort16* Gb16  = (ushort16*)(wsb + G_off);
  (void)V81_off; (void)V82_off;

  // interleaved K/V buffers (256B per node each); KV1/KV2 span the old K8x+V8x
  // regions (contiguous), KV3/KV4 overlay dead buffers at attention time.
  uchar* KV1 = (uchar*)(wsb + K81_off);
  uchar* KV2 = (uchar*)(wsb + K82_off);
  uchar* KV3 = (uchar*)(wsb + ebuf_off);  // ebuf dead after bfill_k
  uchar* KV4 = (uchar*)(wsb + G_off);     // G written only after attention
  ushort16* Q3 = Xb1;                     // X1/X2 written only after attention
  ushort16* Q4 = Xb2;

  ushort16* Wq_sv = wpool + 0 * 16384;
  ushort16* Wk_sv = wpool + 1 * 16384;
  ushort16* Wv_sv = wpool + 2 * 16384;
  ushort16* Wq_cv = wpool + 3 * 16384;
  ushort16* Wk_cv = wpool + 4 * 16384;
  ushort16* Wv_cv = wpool + 5 * 16384;
  ushort16* Wq_sh = wpool + 6 * 16384;
  ushort16* Wk_sh = wpool + 7 * 16384;
  ushort16* Wv_sh = wpool + 8 * 16384;
  ushort16* Wgb   = wpool + 147456;
  ushort16* Wob   = wpool + 180224;
  ushort16* Wohb  = wpool + 212992;
  ushort16* W1b   = wpool + 245760;
  ushort16* W2b   = wpool + 278528;
  ushort16* W1hb  = wpool + 311296;
  ushort16* W2hb  = wpool + 344064;

  const float* bo   = (const float*)d_in[14];
  const float* bo_h = (const float*)d_in[16];
  const float* b1   = (const float*)d_in[18];
  const float* b2   = (const float*)d_in[20];
  const float* b1h  = (const float*)d_in[22];
  const float* b2h  = (const float*)d_in[24];
  const float* bg1  = (const float*)d_in[26];
  const float* bg2  = (const float*)d_in[28];
  const float* gbn1  = (const float*)d_in[29];
  const float* bbn1  = (const float*)d_in[30];
  const float* gbn2  = (const float*)d_in[31];
  const float* bbn2  = (const float*)d_in[32];
  const float* gbn1h = (const float*)d_in[33];
  const float* bbn1h = (const float*)d_in[34];
  const float* gbn2h = (const float*)d_in[35];
  const float* bbn2h = (const float*)d_in[36];

  float* out_h  = (float*)d_out;
  float* out_sv = out_h + (size_t)N * 128;

  (void)hipMemsetAsync(wsb, 0, stats_off + 4 * 256 * 4, stream);

  WConv wc;
  {
    auto set = [&](int i, int din, int din2, size_t dstoff, int KD, int MD){
      wc.e[i].s  = (const float*)d_in[din];
      wc.e[i].s2 = (din2 >= 0) ? (const float*)d_in[din2] : nullptr;
      wc.e[i].d  = wpool + dstoff;
      wc.e[i].KD = KD; wc.e[i].MD = MD;
      wc.e[i].nfrag = KD * MD / 8;
    };
    for (int i = 0; i < 9; i++) set(i, 4 + i, -1, (size_t)i * 16384, 128, 128);
    set(9,  25, 27, 147456, 128, 256);
    set(10, 13, -1, 180224, 256, 128);
    set(11, 15, -1, 212992, 256, 128);
    set(12, 17, -1, 245760, 128, 256);
    set(13, 19, -1, 278528, 256, 128);
    set(14, 21, -1, 311296, 128, 256);
    set(15, 23, -1, 344064, 256, 128);
  }
  conv_w_k<<<dim3(16, 16), 256, 0, stream>>>(wc);

  int nelem = N * 128;
  conv2_k<<<dim3((nelem / 4 + 255) / 256, 2), 256, 0, stream>>>(h, sv, h_f, sv_f, nelem);

  // bucket params: B <= 128 buckets of 2^shift dst values
  int shift = 9;
  while ((((N - 1) >> shift) + 1) > 128) shift++;
  const int B = ((N - 1) >> shift) + 1;

  const int NB = (N + 1023) / 1024;
  hist_k<<<2048, 256, 0, stream>>>(dst, cnt, E);
  scan_part_k<<<NB, 256, 0, stream>>>(cnt, bsum, N);
  scan_top_k<<<1, 64, 0, stream>>>(bsum, NB);
  scan_out_k<<<NB, 256, 0, stream>>>(cnt, bsum, row_off, cursor, bcur, N, E, shift);
  bin_k<<<(E + BIN_TILE - 1) / BIN_TILE, BIN_TB, 0, stream>>>(src, dst, bcur, ebuf, E, shift, B);
  bfill_k<<<B, 512, 0, stream>>>(ebuf, row_off, cursor, esrc, shift, N);

  const int GB = (N + 63) / 64;
  const int AB = (N + 3) / 4;
  const int T4 = nelem / 4;
  const int APB = (T4 + 255) / 256;
  const float invN = 1.f / (float)N;

  // all four QKV projections, then one fused quad-attention pass
  gemm_qkv_k<<<GB, 256, 0, stream>>>(h_f, h_f, Wq_sv, Wk_sv, Wv_sv, Q1, KV1, N);
  gemm_qkv_k<<<GB, 256, 0, stream>>>(h_f, sv_f, Wq_cv, Wk_cv, Wv_cv, Q2, KV2, N);
  gemm_qkv_k<<<GB, 256, 0, stream>>>(sv_f, sv_f, Wq_sh, Wk_sh, Wv_sh, Q3, KV3, N);
  gemm_qkv_k<<<GB, 256, 0, stream>>>(sv_f, h_f, Wq_cv, Wk_cv, Wv_cv, Q4, KV4, N);
  attn4_k<<<AB, 256, 0, stream>>>(Q1, Q2, Q3, Q4, KV1, KV2, KV3, KV4,
                                  row_off, esrc, cat_h, cat_sv, N);

  // ---- h branch ----
  gemm_k<256,128,3,0,1,256><<<GB, 256, 0, stream>>>(cat_h, Wob, bo, nullptr, h_f, nullptr,
      nullptr, nullptr, nullptr, nullptr, nullptr, nullptr, Xb1, stats, N, invN);
  gemm_k<128,256,1,1,0,256><<<GB, 256, 0, stream>>>(Xb1, W1b, b1, nullptr, nullptr, nullptr,
      nullptr, nullptr, nullptr, stats, gbn1, bbn1, cat_h, nullptr, N, invN);
  gemm_k<256,128,5,0,1,256><<<GB, 256, 0, stream>>>(cat_h, W2b, b2, nullptr, Xb1, nullptr,
      stats, gbn1, bbn1, nullptr, nullptr, nullptr, Xb2, stats + 256, N, invN);
  bn_apply_k<<<APB, 256, 0, stream>>>(Xb2, stats + 256, gbn2, bbn2, out_h, T4, invN);

  // ---- sv branch ----
  gemm_k<128,256,2,0,0,256><<<GB, 256, 0, stream>>>(h_f, Wgb, bg1, bg2, nullptr, nullptr,
      nullptr, nullptr, nullptr, nullptr, nullptr, nullptr, Gb16, nullptr, N, invN);
  gemm_k<256,128,4,0,1,256><<<GB, 256, 0, stream>>>(cat_sv, Wohb, bo_h, nullptr, sv_f, Gb16,
      nullptr, nullptr, nullptr, nullptr, nullptr, nullptr, Xb1, stats + 512, N, invN);
  gemm_k<128,256,1,1,0,256><<<GB, 256, 0, stream>>>(Xb1, W1hb, b1h, nullptr, nullptr, nullptr,
      nullptr, nullptr, nullptr, stats + 512, gbn1h, bbn1h, cat_sv, nullptr, N, invN);
  gemm_k<256,128,6,0,1,256><<<GB, 256, 0, stream>>>(cat_sv, W2hb, b2h, nullptr, Xb1, Gb16 + 128,
      stats + 512, gbn1h, bbn1h, nullptr, nullptr, nullptr, Xb2, stats + 768, N, invN);
  bn_apply_k<<<APB, 256, 0, stream>>>(Xb2, stats + 768, gbn2h, bbn2h, out_sv, T4, invN);
}